// Round 16
// baseline (589.596 us; speedup 1.0000x reference)
//
#include <hip/hip_runtime.h>

typedef __bf16 bf16x8 __attribute__((ext_vector_type(8)));
typedef __bf16 bf16x4 __attribute__((ext_vector_type(4)));
typedef float f32x4 __attribute__((ext_vector_type(4)));

#define MFMA(a,b,c) __builtin_amdgcn_mfma_f32_16x16x32_bf16(a, b, c, 0, 0, 0)

__device__ __forceinline__ float gelu_f(float t) {
    float t2 = t * t;
    float m = t * __builtin_fmaf(-0.07135481627f, t2, -1.5957691216f); // -2z
    float e = __expf(m);
    return t * __builtin_amdgcn_rcpf(1.0f + e);
}

// ---------------- kernel 0: weight prep (transpose + bf16, fold qk scale) ----------------
__global__ void prep_weights(const float* __restrict__ wq, const float* __restrict__ wkv,
                             const float* __restrict__ wp, const float* __restrict__ w1,
                             const float* __restrict__ w2, __bf16* __restrict__ ws) {
    int i = blockIdx.x * 256 + threadIdx.x;
    const float scale = 0.17677669529663687f; // 1/sqrt(32)
    if (i < 9216) {                       // wqt[n][k] = wq[k][n]*scale
        int n = i / 96, k = i % 96;
        ws[i] = (__bf16)(wq[k * 96 + n] * scale);
    } else if (i < 27648) {               // wkvt[n][k], n in [0,192)
        int j = i - 9216; int n = j / 96, k = j % 96;
        ws[i] = (__bf16)(wkv[k * 192 + n]);
    } else if (i < 36864) {               // wpt[n][k]
        int j = i - 27648; int n = j / 96, k = j % 96;
        ws[i] = (__bf16)(wp[k * 96 + n]);
    } else if (i < 73728) {               // w1t[n][k], n in [0,384), k in [0,96)
        int j = i - 36864; int n = j / 96, k = j % 96;
        ws[i] = (__bf16)(w1[k * 384 + n]);
    } else if (i < 110592) {              // w2t[n][k], n in [0,96), k in [0,384)
        int j = i - 73728; int n = j / 384, k = j % 384;
        ws[i] = (__bf16)(w2[k * 96 + n]);
    }
}

// ---------------- kernel 1: LN1 + window attention + proj + residual (R2 internals, 8 waves) ----------------
#define LDH 104

__global__ __launch_bounds__(512) void attn_kernel(
    const float* __restrict__ x, const float* __restrict__ g1v, const float* __restrict__ b1v,
    const float* __restrict__ bq, const float* __restrict__ bkv, const float* __restrict__ bp,
    const __bf16* __restrict__ ws, float* __restrict__ xmid)
{
    const __bf16* wqt  = ws;
    const __bf16* wkvt = ws + 9216;
    const __bf16* wpt  = ws + 27648;

    __shared__ __align__(16) __bf16 h_lds[64 * LDH];    // h, later attn_out
    __shared__ __align__(16) __bf16 q_lds[64 * LDH];    // q, later proj out
    __shared__ __align__(16) __bf16 k_lds[64 * LDH];
    __shared__ __align__(16) __bf16 vt_lds[96 * 72];    // v transposed [vcol][tok]
    __shared__ __align__(16) __bf16 p_lds[8 * 16 * 72]; // per-wave P scratch

    const int tid = threadIdx.x;
    const int wv = tid >> 6, lane = tid & 63;
    const int c = lane & 15, g = lane >> 4;
    const int mq = wv >> 1, nh = wv & 1;     // wave's m-tile and n-triple for QKV/proj

    const int wid = blockIdx.x;
    const int wdI = wid / 576, rem = wid % 576, whI = rem / 24, wwI = rem % 24;
    const int tok = tid >> 3, cs = (tid & 7) * 12;      // 8 threads per token, 12 cols each
    const int dz = tok >> 4, hy = (tok >> 2) & 3, wx = tok & 3;
    const long gbase = (((long)(wdI * 4 + dz) * 96 + (whI * 4 + hy)) * 96 + (wwI * 4 + wx)) * 96 + cs;

    const f32x4 fzero = {0.f, 0.f, 0.f, 0.f};

    // ---- phase 0: load x, LN1 -> h_lds ----
    float xr[12];
    #pragma unroll
    for (int j = 0; j < 3; ++j) {
        float4 v = *reinterpret_cast<const float4*>(x + gbase + j * 4);
        xr[j*4+0] = v.x; xr[j*4+1] = v.y; xr[j*4+2] = v.z; xr[j*4+3] = v.w;
    }
    {
        float s = 0.f;
        #pragma unroll
        for (int j = 0; j < 12; ++j) s += xr[j];
        s += __shfl_xor(s, 1); s += __shfl_xor(s, 2); s += __shfl_xor(s, 4);
        float mu = s * (1.0f / 96.0f);
        float vs = 0.f;
        #pragma unroll
        for (int j = 0; j < 12; ++j) { float d = xr[j] - mu; vs += d * d; }
        vs += __shfl_xor(vs, 1); vs += __shfl_xor(vs, 2); vs += __shfl_xor(vs, 4);
        float rstd = rsqrtf(vs * (1.0f / 96.0f) + 1e-5f);
        #pragma unroll
        for (int j = 0; j < 3; ++j) {
            f32x4 gv = *reinterpret_cast<const f32x4*>(g1v + cs + j * 4);
            f32x4 bv = *reinterpret_cast<const f32x4*>(b1v + cs + j * 4);
            bf16x4 o;
            #pragma unroll
            for (int r = 0; r < 4; ++r) o[r] = (__bf16)((xr[j*4+r] - mu) * rstd * gv[r] + bv[r]);
            *reinterpret_cast<bf16x4*>(&h_lds[tok * LDH + cs + j*4]) = o;
        }
    }
    __syncthreads();  // bar1: h ready

    // ---- phase 1: QKV. wave: m-tile mq, n-triple nh (9 MFMA each) ----
    {   // q
        f32x4 acc[3];
        #pragma unroll
        for (int nl = 0; nl < 3; ++nl) acc[nl] = fzero;
        #pragma unroll
        for (int kc = 0; kc < 3; ++kc) {
            bf16x8 a = *reinterpret_cast<const bf16x8*>(&h_lds[(mq*16 + c) * LDH + kc*32 + g*8]);
            #pragma unroll
            for (int nl = 0; nl < 3; ++nl) {
                int nt = nh * 3 + nl;
                bf16x8 b = *reinterpret_cast<const bf16x8*>(&wqt[(nt*16 + c) * 96 + kc*32 + g*8]);
                acc[nl] = MFMA(a, b, acc[nl]);
            }
        }
        #pragma unroll
        for (int nl = 0; nl < 3; ++nl) {
            int n = (nh * 3 + nl) * 16 + c;
            float bias = bq[n] * 0.17677669529663687f;
            #pragma unroll
            for (int r = 0; r < 4; ++r)
                q_lds[(mq*16 + g*4 + r) * LDH + n] = (__bf16)(acc[nl][r] + bias);
        }
    }
    {   // k
        f32x4 acc[3];
        #pragma unroll
        for (int nl = 0; nl < 3; ++nl) acc[nl] = fzero;
        #pragma unroll
        for (int kc = 0; kc < 3; ++kc) {
            bf16x8 a = *reinterpret_cast<const bf16x8*>(&h_lds[(mq*16 + c) * LDH + kc*32 + g*8]);
            #pragma unroll
            for (int nl = 0; nl < 3; ++nl) {
                int nt = nh * 3 + nl;
                bf16x8 b = *reinterpret_cast<const bf16x8*>(&wkvt[(nt*16 + c) * 96 + kc*32 + g*8]);
                acc[nl] = MFMA(a, b, acc[nl]);
            }
        }
        #pragma unroll
        for (int nl = 0; nl < 3; ++nl) {
            int n = (nh * 3 + nl) * 16 + c;
            float bias = bkv[n];
            #pragma unroll
            for (int r = 0; r < 4; ++r)
                k_lds[(mq*16 + g*4 + r) * LDH + n] = (__bf16)(acc[nl][r] + bias);
        }
    }
    {   // v -> vt
        f32x4 av[3];
        #pragma unroll
        for (int nl = 0; nl < 3; ++nl) av[nl] = fzero;
        #pragma unroll
        for (int kc = 0; kc < 3; ++kc) {
            bf16x8 aH = *reinterpret_cast<const bf16x8*>(&h_lds[(mq*16 + c) * LDH + kc*32 + g*8]);
            #pragma unroll
            for (int nl = 0; nl < 3; ++nl) {
                int nv = nh * 3 + nl;
                bf16x8 bW = *reinterpret_cast<const bf16x8*>(&wkvt[(96 + nv*16 + c) * 96 + kc*32 + g*8]);
                av[nl] = MFMA(aH, bW, av[nl]);
            }
        }
        #pragma unroll
        for (int nl = 0; nl < 3; ++nl) {
            int nv = nh * 3 + nl;
            float bias = bkv[96 + nv*16 + c];
            bf16x4 pk;
            #pragma unroll
            for (int r = 0; r < 4; ++r) pk[r] = (__bf16)(av[nl][r] + bias);
            *reinterpret_cast<bf16x4*>(&vt_lds[(nv*16 + c) * 72 + mq*16 + g*4]) = pk;
        }
    }
    __syncthreads();  // bar2: q, k, vt ready

    // ---- phase 2: attention. waves 0-3: qt=wv, heads {0,2}; waves 4-7: qt=wv-4, head {1} ----
    {
        const int qt = (wv < 4) ? wv : wv - 4;
        const int nheads = (wv < 4) ? 2 : 1;
        __bf16* p_w = &p_lds[wv * (16 * 72)];
        for (int hi = 0; hi < nheads; ++hi) {
            const int h = (wv < 4) ? (hi == 0 ? 0 : 2) : 1;
            f32x4 sacc[4];
            #pragma unroll
            for (int nt = 0; nt < 4; ++nt) sacc[nt] = fzero;
            bf16x8 a = *reinterpret_cast<const bf16x8*>(&q_lds[(qt*16 + c) * LDH + h*32 + g*8]);
            #pragma unroll
            for (int nt = 0; nt < 4; ++nt) {
                bf16x8 b = *reinterpret_cast<const bf16x8*>(&k_lds[(nt*16 + c) * LDH + h*32 + g*8]);
                sacc[nt] = MFMA(a, b, sacc[nt]);
            }
            float mx[4];
            #pragma unroll
            for (int r = 0; r < 4; ++r) {
                float m0 = fmaxf(fmaxf(sacc[0][r], sacc[1][r]), fmaxf(sacc[2][r], sacc[3][r]));
                m0 = fmaxf(m0, __shfl_xor(m0, 1));
                m0 = fmaxf(m0, __shfl_xor(m0, 2));
                m0 = fmaxf(m0, __shfl_xor(m0, 4));
                m0 = fmaxf(m0, __shfl_xor(m0, 8));
                mx[r] = m0;
            }
            float p[4][4];
            #pragma unroll
            for (int nt = 0; nt < 4; ++nt)
                #pragma unroll
                for (int r = 0; r < 4; ++r)
                    p[nt][r] = __expf(sacc[nt][r] - mx[r]);
            float rsinv[4];
            #pragma unroll
            for (int r = 0; r < 4; ++r) {
                float s0 = p[0][r] + p[1][r] + p[2][r] + p[3][r];
                s0 += __shfl_xor(s0, 1); s0 += __shfl_xor(s0, 2);
                s0 += __shfl_xor(s0, 4); s0 += __shfl_xor(s0, 8);
                rsinv[r] = __builtin_amdgcn_rcpf(s0);
            }
            #pragma unroll
            for (int nt = 0; nt < 4; ++nt)
                #pragma unroll
                for (int r = 0; r < 4; ++r)
                    p_w[(g*4 + r) * 72 + nt*16 + c] = (__bf16)p[nt][r];

            f32x4 oacc[2];
            oacc[0] = fzero; oacc[1] = fzero;
            #pragma unroll
            for (int kc = 0; kc < 2; ++kc) {
                bf16x8 pa = *reinterpret_cast<const bf16x8*>(&p_w[c * 72 + kc*32 + g*8]);
                #pragma unroll
                for (int n2 = 0; n2 < 2; ++n2) {
                    bf16x8 b = *reinterpret_cast<const bf16x8*>(&vt_lds[(h*32 + n2*16 + c) * 72 + kc*32 + g*8]);
                    oacc[n2] = MFMA(pa, b, oacc[n2]);
                }
            }
            #pragma unroll
            for (int n2 = 0; n2 < 2; ++n2)
                #pragma unroll
                for (int r = 0; r < 4; ++r)
                    h_lds[(qt*16 + g*4 + r) * LDH + h*32 + n2*16 + c] = (__bf16)(oacc[n2][r] * rsinv[r]);
        }
    }
    __syncthreads();  // bar3: attn_out complete; q_lds free

    // ---- phase 3: proj. wave: m-tile mq, n-triple nh (9 MFMA) -> q_lds ----
    {
        f32x4 acc[3];
        #pragma unroll
        for (int nl = 0; nl < 3; ++nl) acc[nl] = fzero;
        #pragma unroll
        for (int kc = 0; kc < 3; ++kc) {
            bf16x8 a = *reinterpret_cast<const bf16x8*>(&h_lds[(mq*16 + c) * LDH + kc*32 + g*8]);
            #pragma unroll
            for (int nl = 0; nl < 3; ++nl) {
                int nt = nh * 3 + nl;
                bf16x8 b = *reinterpret_cast<const bf16x8*>(&wpt[(nt*16 + c) * 96 + kc*32 + g*8]);
                acc[nl] = MFMA(a, b, acc[nl]);
            }
        }
        #pragma unroll
        for (int nl = 0; nl < 3; ++nl) {
            int n = (nh * 3 + nl) * 16 + c;
            float bias = bp[n];
            #pragma unroll
            for (int r = 0; r < 4; ++r)
                q_lds[(mq*16 + g*4 + r) * LDH + n] = (__bf16)(acc[nl][r] + bias);
        }
    }
    __syncthreads();  // bar4: proj out ready

    // ---- phase 4: residual store ----
    #pragma unroll
    for (int j = 0; j < 3; ++j) {
        bf16x4 pr = *reinterpret_cast<const bf16x4*>(&q_lds[tok * LDH + cs + j*4]);
        float4 v;
        v.x = xr[j*4+0] + (float)pr[0];
        v.y = xr[j*4+1] + (float)pr[1];
        v.z = xr[j*4+2] + (float)pr[2];
        v.w = xr[j*4+3] + (float)pr[3];
        *reinterpret_cast<float4*>(xmid + gbase + j * 4) = v;
    }
}

// ---------------- kernel 2: LN2 + MLP + residual (384 thr, chunk-pair 192, 64 tok) ----------------
#define LDU 104
#define LDCH 200   // 192 cols + pad

__global__ __launch_bounds__(384, 4) void mlp_kernel(
    float* __restrict__ xio, const float* __restrict__ g2v, const float* __restrict__ b2v,
    const float* __restrict__ bm1, const float* __restrict__ bm2,
    const __bf16* __restrict__ ws)
{
    const __bf16* w1t = ws + 36864;
    const __bf16* w2t = ws + 73728;

    __shared__ __align__(16) __bf16 u_lds[64 * LDU];    // 13312 B
    __shared__ __align__(16) __bf16 hid[64 * LDCH];     // 25600 B -> total 38912 B (4 blk/CU)

    const int tid = threadIdx.x;
    const int wv = tid >> 6, lane = tid & 63;     // wv in [0,6)
    const int c = lane & 15, g = lane >> 4;

    const int tok = tid >> 2, cseg = (tid & 3) * 24;   // valid for tid<256
    const long gaddr = ((long)blockIdx.x * 64 + tok) * 96 + cseg;

    const f32x4 fzero = {0.f, 0.f, 0.f, 0.f};

    // ---- LN2 -> u_lds (threads 0..255) ----
    if (tid < 256) {
        float xr[24];
        #pragma unroll
        for (int j = 0; j < 6; ++j) {
            float4 v = *reinterpret_cast<const float4*>(xio + gaddr + j * 4);
            xr[j*4+0] = v.x; xr[j*4+1] = v.y; xr[j*4+2] = v.z; xr[j*4+3] = v.w;
        }
        float s = 0.f;
        #pragma unroll
        for (int j = 0; j < 24; ++j) s += xr[j];
        s += __shfl_xor(s, 1); s += __shfl_xor(s, 2);
        float mu = s * (1.0f / 96.0f);
        float vs = 0.f;
        #pragma unroll
        for (int j = 0; j < 24; ++j) { float d = xr[j] - mu; vs += d * d; }
        vs += __shfl_xor(vs, 1); vs += __shfl_xor(vs, 2);
        float rstd = rsqrtf(vs * (1.0f / 96.0f) + 1e-5f);
        #pragma unroll
        for (int j = 0; j < 6; ++j) {
            f32x4 gv = *reinterpret_cast<const f32x4*>(g2v + cseg + j * 4);
            f32x4 bv = *reinterpret_cast<const f32x4*>(b2v + cseg + j * 4);
            bf16x4 o;
            #pragma unroll
            for (int r = 0; r < 4; ++r) o[r] = (__bf16)((xr[j*4+r] - mu) * rstd * gv[r] + bv[r]);
            *reinterpret_cast<bf16x4*>(&u_lds[tok * LDU + cseg + j*4]) = o;
        }
    }
    __syncthreads();  // u ready

    // ---- MLP: 2 chunk-pairs of 192 hidden; wave wv owns hid-tiles (wv, wv+6) and out-tile wv ----
    f32x4 accB[4];
    #pragma unroll
    for (int tt = 0; tt < 4; ++tt) accB[tt] = fzero;

    #pragma unroll
    for (int chp = 0; chp < 2; ++chp) {
        // hoist this pair's w2 fragments (K=192) — latency hides under A-phase MFMAs
        bf16x8 aW2[6];
        #pragma unroll
        for (int kc2 = 0; kc2 < 6; ++kc2)
            aW2[kc2] = *reinterpret_cast<const bf16x8*>(&w2t[(wv*16 + c) * 384 + chp*192 + kc2*32 + g*8]);

        // A-phase: two independent hid-tiles (chp*12+wv) and (chp*12+6+wv)
        f32x4 accA0[4], accA1[4];
        #pragma unroll
        for (int tt = 0; tt < 4; ++tt) { accA0[tt] = fzero; accA1[tt] = fzero; }
        #pragma unroll
        for (int kc = 0; kc < 3; ++kc) {
            bf16x8 aW0 = *reinterpret_cast<const bf16x8*>(&w1t[((chp*12 + wv)*16 + c) * 96 + kc*32 + g*8]);
            bf16x8 aW1 = *reinterpret_cast<const bf16x8*>(&w1t[((chp*12 + 6 + wv)*16 + c) * 96 + kc*32 + g*8]);
            #pragma unroll
            for (int tt = 0; tt < 4; ++tt) {
                bf16x8 bU = *reinterpret_cast<const bf16x8*>(&u_lds[(tt*16 + c) * LDU + kc*32 + g*8]);
                accA0[tt] = MFMA(aW0, bU, accA0[tt]);
                accA1[tt] = MFMA(aW1, bU, accA1[tt]);
            }
        }
        {
            f32x4 bb0 = *reinterpret_cast<const f32x4*>(&bm1[(chp*12 + wv)*16 + 4*g]);
            f32x4 bb1 = *reinterpret_cast<const f32x4*>(&bm1[(chp*12 + 6 + wv)*16 + 4*g]);
            #pragma unroll
            for (int tt = 0; tt < 4; ++tt) {
                bf16x4 o0, o1;
                #pragma unroll
                for (int r = 0; r < 4; ++r) {
                    o0[r] = (__bf16)gelu_f(accA0[tt][r] + bb0[r]);
                    o1[r] = (__bf16)gelu_f(accA1[tt][r] + bb1[r]);
                }
                *reinterpret_cast<bf16x4*>(&hid[(tt*16 + c) * LDCH + wv*16 + 4*g]) = o0;
                *reinterpret_cast<bf16x4*>(&hid[(tt*16 + c) * LDCH + 96 + wv*16 + 4*g]) = o1;
            }
        }
        __syncthreads();  // hid (192 cols) ready

        // B-phase: out-tile wv, K = 192
        #pragma unroll
        for (int kc2 = 0; kc2 < 6; ++kc2) {
            #pragma unroll
            for (int tt = 0; tt < 4; ++tt) {
                bf16x8 bHd = *reinterpret_cast<const bf16x8*>(&hid[(tt*16 + c) * LDCH + kc2*32 + g*8]);
                accB[tt] = MFMA(aW2[kc2], bHd, accB[tt]);
            }
        }
        if (chp == 0) __syncthreads();  // protect hid overwrite by next pair
    }

    // ---- epilogue: value(tok=tt*16+c, outcol=wv*16+4g+r) -> u_lds (u is dead) ----
    {
        f32x4 bb = *reinterpret_cast<const f32x4*>(&bm2[wv*16 + 4*g]);
        #pragma unroll
        for (int tt = 0; tt < 4; ++tt) {
            bf16x4 o;
            #pragma unroll
            for (int r = 0; r < 4; ++r) o[r] = (__bf16)(accB[tt][r] + bb[r]);
            *reinterpret_cast<bf16x4*>(&u_lds[(tt*16 + c) * LDU + wv*16 + 4*g]) = o;
        }
    }
    __syncthreads();  // cross-wave epilogue exchange

    // ---- residual: out = x + mlp (threads 0..255; re-read x, L2-resident) ----
    if (tid < 256) {
        #pragma unroll
        for (int j = 0; j < 6; ++j) {
            float4 xv = *reinterpret_cast<const float4*>(xio + gaddr + j * 4);
            bf16x4 mo = *reinterpret_cast<const bf16x4*>(&u_lds[tok * LDU + cseg + j*4]);
            float4 v;
            v.x = xv.x + (float)mo[0];
            v.y = xv.y + (float)mo[1];
            v.z = xv.z + (float)mo[2];
            v.w = xv.w + (float)mo[3];
            *reinterpret_cast<float4*>(xio + gaddr + j * 4) = v;
        }
    }
}

extern "C" void kernel_launch(void* const* d_in, const int* in_sizes, int n_in,
                              void* d_out, int out_size, void* d_ws, size_t ws_size,
                              hipStream_t stream) {
    (void)in_sizes; (void)n_in; (void)out_size; (void)ws_size;
    const float* x   = (const float*)d_in[0];
    const float* g1  = (const float*)d_in[1];
    const float* b1  = (const float*)d_in[2];
    const float* wq  = (const float*)d_in[3];
    const float* bq  = (const float*)d_in[4];
    const float* wkv = (const float*)d_in[5];
    const float* bkv = (const float*)d_in[6];
    const float* wp  = (const float*)d_in[7];
    const float* bp  = (const float*)d_in[8];
    const float* g2  = (const float*)d_in[9];
    const float* b2  = (const float*)d_in[10];
    const float* w1  = (const float*)d_in[11];
    const float* bm1 = (const float*)d_in[12];
    const float* w2  = (const float*)d_in[13];
    const float* bm2 = (const float*)d_in[14];
    float* out = (float*)d_out;
    __bf16* ws = (__bf16*)d_ws;

    prep_weights<<<432, 256, 0, stream>>>(wq, wkv, wp, w1, w2, ws);
    attn_kernel<<<9216, 512, 0, stream>>>(x, g1, b1, bq, bkv, bp, ws, out);
    mlp_kernel<<<9216, 384, 0, stream>>>(out, g2, b2, bm1, bm2, ws);
}

// Round 17
// 464.191 us; speedup vs baseline: 1.2702x; 1.2702x over previous
//
#include <hip/hip_runtime.h>

typedef __bf16 bf16x8 __attribute__((ext_vector_type(8)));
typedef __bf16 bf16x4 __attribute__((ext_vector_type(4)));
typedef float f32x4 __attribute__((ext_vector_type(4)));

#define MFMA(a,b,c) __builtin_amdgcn_mfma_f32_16x16x32_bf16(a, b, c, 0, 0, 0)

__device__ __forceinline__ float gelu_f(float t) {
    float t2 = t * t;
    float m = t * __builtin_fmaf(-0.07135481627f, t2, -1.5957691216f); // -2z
    float e = __expf(m);
    return t * __builtin_amdgcn_rcpf(1.0f + e);
}

// ---------------- kernel 2 (defined FIRST: rule-#19 codegen-context probe):
// LN2 + MLP + residual (384 threads, chunk=96; R7-measured structure) ----------------
#define LDU 104
#define LDC2 104

__global__ __launch_bounds__(384, 4) void mlp_kernel(
    float* __restrict__ xio, const float* __restrict__ g2v, const float* __restrict__ b2v,
    const float* __restrict__ bm1, const float* __restrict__ bm2,
    const __bf16* __restrict__ ws)
{
    const __bf16* w1t = ws + 36864;
    const __bf16* w2t = ws + 73728;

    __shared__ __align__(16) __bf16 u_lds[64 * LDU];     // 13312 B
    __shared__ __align__(16) __bf16 hid[64 * LDC2];      // 13312 B -> total 26624 B

    const int tid = threadIdx.x;
    const int wv = tid >> 6, lane = tid & 63;     // wv in [0,6)
    const int c = lane & 15, g = lane >> 4;

    const int tok = tid >> 2, cseg = (tid & 3) * 24;   // valid for tid<256
    const long gaddr = ((long)blockIdx.x * 64 + tok) * 96 + cseg;

    const f32x4 fzero = {0.f, 0.f, 0.f, 0.f};

    // ---- LN2 -> u_lds (threads 0..255) ----
    if (tid < 256) {
        float xr[24];
        #pragma unroll
        for (int j = 0; j < 6; ++j) {
            float4 v = *reinterpret_cast<const float4*>(xio + gaddr + j * 4);
            xr[j*4+0] = v.x; xr[j*4+1] = v.y; xr[j*4+2] = v.z; xr[j*4+3] = v.w;
        }
        float s = 0.f;
        #pragma unroll
        for (int j = 0; j < 24; ++j) s += xr[j];
        s += __shfl_xor(s, 1); s += __shfl_xor(s, 2);
        float mu = s * (1.0f / 96.0f);
        float vs = 0.f;
        #pragma unroll
        for (int j = 0; j < 24; ++j) { float d = xr[j] - mu; vs += d * d; }
        vs += __shfl_xor(vs, 1); vs += __shfl_xor(vs, 2);
        float rstd = rsqrtf(vs * (1.0f / 96.0f) + 1e-5f);
        #pragma unroll
        for (int j = 0; j < 6; ++j) {
            f32x4 gv = *reinterpret_cast<const f32x4*>(g2v + cseg + j * 4);
            f32x4 bv = *reinterpret_cast<const f32x4*>(b2v + cseg + j * 4);
            bf16x4 o;
            #pragma unroll
            for (int r = 0; r < 4; ++r) o[r] = (__bf16)((xr[j*4+r] - mu) * rstd * gv[r] + bv[r]);
            *reinterpret_cast<bf16x4*>(&u_lds[tok * LDU + cseg + j*4]) = o;
        }
    }
    __syncthreads();  // bar: u ready

    // ---- MLP: 4 chunks of 96 hidden; wave wv owns hid-tile wv and out-tile wv ----
    f32x4 accB[4];
    #pragma unroll
    for (int tt = 0; tt < 4; ++tt) accB[tt] = fzero;

    #pragma unroll
    for (int ch = 0; ch < 4; ++ch) {
        // GEMM A: hid-tile (ch*6+wv): A = w1 rows, B = token tiles
        f32x4 accA[4];
        #pragma unroll
        for (int tt = 0; tt < 4; ++tt) accA[tt] = fzero;
        #pragma unroll
        for (int kc = 0; kc < 3; ++kc) {
            bf16x8 aW = *reinterpret_cast<const bf16x8*>(&w1t[((ch*6 + wv)*16 + c) * 96 + kc*32 + g*8]);
            #pragma unroll
            for (int tt = 0; tt < 4; ++tt) {
                bf16x8 bU = *reinterpret_cast<const bf16x8*>(&u_lds[(tt*16 + c) * LDU + kc*32 + g*8]);
                accA[tt] = MFMA(aW, bU, accA[tt]);
            }
        }
        {
            f32x4 bb = *reinterpret_cast<const f32x4*>(&bm1[(ch*6 + wv)*16 + 4*g]);
            #pragma unroll
            for (int tt = 0; tt < 4; ++tt) {
                bf16x4 o;
                #pragma unroll
                for (int r = 0; r < 4; ++r) o[r] = (__bf16)gelu_f(accA[tt][r] + bb[r]);
                *reinterpret_cast<bf16x4*>(&hid[(tt*16 + c) * LDC2 + wv*16 + 4*g]) = o;
            }
        }
        __syncthreads();  // hid ready

        // GEMM B: out-tile wv: A = w2 rows (out cols), B = token tiles. K = 96 chunk
        #pragma unroll
        for (int kc = 0; kc < 3; ++kc) {
            bf16x8 aW2 = *reinterpret_cast<const bf16x8*>(&w2t[(wv*16 + c) * 384 + ch*96 + kc*32 + g*8]);
            #pragma unroll
            for (int tt = 0; tt < 4; ++tt) {
                bf16x8 bHd = *reinterpret_cast<const bf16x8*>(&hid[(tt*16 + c) * LDC2 + kc*32 + g*8]);
                accB[tt] = MFMA(aW2, bHd, accB[tt]);
            }
        }
        if (ch < 3) __syncthreads();  // protect hid overwrite by next chunk
    }

    // ---- epilogue: value(tok=tt*16+c, outcol=wv*16+4g+r) -> u_lds (u is dead) ----
    {
        f32x4 bb = *reinterpret_cast<const f32x4*>(&bm2[wv*16 + 4*g]);
        #pragma unroll
        for (int tt = 0; tt < 4; ++tt) {
            bf16x4 o;
            #pragma unroll
            for (int r = 0; r < 4; ++r) o[r] = (__bf16)(accB[tt][r] + bb[r]);
            *reinterpret_cast<bf16x4*>(&u_lds[(tt*16 + c) * LDU + wv*16 + 4*g]) = o;
        }
    }
    __syncthreads();  // cross-wave epilogue exchange

    // ---- residual: out = x + mlp (threads 0..255; re-read x, L2-resident) ----
    if (tid < 256) {
        #pragma unroll
        for (int j = 0; j < 6; ++j) {
            float4 xv = *reinterpret_cast<const float4*>(xio + gaddr + j * 4);
            bf16x4 mo = *reinterpret_cast<const bf16x4*>(&u_lds[tok * LDU + cseg + j*4]);
            float4 v;
            v.x = xv.x + (float)mo[0];
            v.y = xv.y + (float)mo[1];
            v.z = xv.z + (float)mo[2];
            v.w = xv.w + (float)mo[3];
            *reinterpret_cast<float4*>(xio + gaddr + j * 4) = v;
        }
    }
}

// ---------------- kernel 0: weight prep (transpose + bf16, fold qk scale) ----------------
__global__ void prep_weights(const float* __restrict__ wq, const float* __restrict__ wkv,
                             const float* __restrict__ wp, const float* __restrict__ w1,
                             const float* __restrict__ w2, __bf16* __restrict__ ws) {
    int i = blockIdx.x * 256 + threadIdx.x;
    const float scale = 0.17677669529663687f; // 1/sqrt(32)
    if (i < 9216) {                       // wqt[n][k] = wq[k][n]*scale
        int n = i / 96, k = i % 96;
        ws[i] = (__bf16)(wq[k * 96 + n] * scale);
    } else if (i < 27648) {               // wkvt[n][k], n in [0,192)
        int j = i - 9216; int n = j / 96, k = j % 96;
        ws[i] = (__bf16)(wkv[k * 192 + n]);
    } else if (i < 36864) {               // wpt[n][k]
        int j = i - 27648; int n = j / 96, k = j % 96;
        ws[i] = (__bf16)(wp[k * 96 + n]);
    } else if (i < 73728) {               // w1t[n][k], n in [0,384), k in [0,96)
        int j = i - 36864; int n = j / 96, k = j % 96;
        ws[i] = (__bf16)(w1[k * 384 + n]);
    } else if (i < 110592) {              // w2t[n][k], n in [0,96), k in [0,384)
        int j = i - 73728; int n = j / 384, k = j % 384;
        ws[i] = (__bf16)(w2[k * 96 + n]);
    }
}

// ---------------- kernel 1: LN1 + window attention + proj + residual (R2-measured) ----------------
#define LDH 104

__global__ __launch_bounds__(256, 2) void attn_kernel(
    const float* __restrict__ x, const float* __restrict__ g1v, const float* __restrict__ b1v,
    const float* __restrict__ bq, const float* __restrict__ bkv, const float* __restrict__ bp,
    const __bf16* __restrict__ ws, float* __restrict__ xmid)
{
    const __bf16* wqt  = ws;
    const __bf16* wkvt = ws + 9216;
    const __bf16* wpt  = ws + 27648;

    __shared__ __align__(16) __bf16 h_lds[64 * LDH];   // h, later attn_out
    __shared__ __align__(16) __bf16 q_lds[64 * LDH];   // q, later proj out
    __shared__ __align__(16) __bf16 k_lds[64 * LDH];
    __shared__ __align__(16) __bf16 vt_lds[96 * 72];   // v transposed [vcol][tok]
    __shared__ __align__(16) __bf16 p_lds[4 * 16 * 72]; // per-wave P scratch

    const int tid = threadIdx.x;
    const int wv = tid >> 6, lane = tid & 63;
    const int c = lane & 15, g = lane >> 4;
    const int mp = wv >> 1, ng = wv & 1;

    const int wid = blockIdx.x;
    const int wdI = wid / 576, rem = wid % 576, whI = rem / 24, wwI = rem % 24;
    const int tok = tid >> 2, cseg = (tid & 3) * 24;
    const int dz = tok >> 4, hy = (tok >> 2) & 3, wx = tok & 3;
    const long gbase = (((long)(wdI * 4 + dz) * 96 + (whI * 4 + hy)) * 96 + (wwI * 4 + wx)) * 96 + cseg;

    // ---- load x window to regs, LN1 -> h_lds (bf16) ----
    float xr[24];
    #pragma unroll
    for (int j = 0; j < 6; ++j) {
        float4 v = *reinterpret_cast<const float4*>(x + gbase + j * 4);
        xr[j*4+0] = v.x; xr[j*4+1] = v.y; xr[j*4+2] = v.z; xr[j*4+3] = v.w;
    }
    float s = 0.f;
    #pragma unroll
    for (int j = 0; j < 24; ++j) s += xr[j];
    s += __shfl_xor(s, 1); s += __shfl_xor(s, 2);
    float mu = s * (1.0f / 96.0f);
    float vs = 0.f;
    #pragma unroll
    for (int j = 0; j < 24; ++j) { float d = xr[j] - mu; vs += d * d; }
    vs += __shfl_xor(vs, 1); vs += __shfl_xor(vs, 2);
    float rstd = rsqrtf(vs * (1.0f / 96.0f) + 1e-5f);
    #pragma unroll
    for (int j = 0; j < 6; ++j) {
        float4 gv = *reinterpret_cast<const float4*>(g1v + cseg + j * 4);
        float4 bv = *reinterpret_cast<const float4*>(b1v + cseg + j * 4);
        h_lds[tok * LDH + cseg + j*4+0] = (__bf16)((xr[j*4+0] - mu) * rstd * gv.x + bv.x);
        h_lds[tok * LDH + cseg + j*4+1] = (__bf16)((xr[j*4+1] - mu) * rstd * gv.y + bv.y);
        h_lds[tok * LDH + cseg + j*4+2] = (__bf16)((xr[j*4+2] - mu) * rstd * gv.z + bv.z);
        h_lds[tok * LDH + cseg + j*4+3] = (__bf16)((xr[j*4+3] - mu) * rstd * gv.w + bv.w);
    }
    __syncthreads();

    // ---- GEMM1: q = h @ wqt (+ bq*scale). wave -> (m-pair mp, 3 n-tiles ng*3..) ----
    {
        f32x4 acc[2][3];
        #pragma unroll
        for (int mi = 0; mi < 2; ++mi)
            #pragma unroll
            for (int nl = 0; nl < 3; ++nl) acc[mi][nl] = (f32x4){0.f, 0.f, 0.f, 0.f};
        #pragma unroll
        for (int kc = 0; kc < 3; ++kc) {
            bf16x8 a[2];
            #pragma unroll
            for (int mi = 0; mi < 2; ++mi)
                a[mi] = *reinterpret_cast<const bf16x8*>(&h_lds[((mp*2+mi)*16 + c) * LDH + kc*32 + g*8]);
            #pragma unroll
            for (int nl = 0; nl < 3; ++nl) {
                int nt = ng * 3 + nl;
                bf16x8 b = *reinterpret_cast<const bf16x8*>(&wqt[(nt*16 + c) * 96 + kc*32 + g*8]);
                #pragma unroll
                for (int mi = 0; mi < 2; ++mi)
                    acc[mi][nl] = MFMA(a[mi], b, acc[mi][nl]);
            }
        }
        #pragma unroll
        for (int nl = 0; nl < 3; ++nl) {
            int n = (ng * 3 + nl) * 16 + c;
            float bias = bq[n] * 0.17677669529663687f;
            #pragma unroll
            for (int mi = 0; mi < 2; ++mi)
                #pragma unroll
                for (int r = 0; r < 4; ++r)
                    q_lds[((mp*2+mi)*16 + g*4 + r) * LDH + n] = (__bf16)(acc[mi][nl][r] + bias);
        }
    }

    // ---- GEMM2: kv = h @ wkvt (+bkv). wave -> 3 of 12 n-tiles, all 4 m-tiles ----
    {
        f32x4 acc[4][3];
        #pragma unroll
        for (int m = 0; m < 4; ++m)
            #pragma unroll
            for (int nl = 0; nl < 3; ++nl) acc[m][nl] = (f32x4){0.f, 0.f, 0.f, 0.f};
        #pragma unroll
        for (int kc = 0; kc < 3; ++kc) {
            bf16x8 a[4];
            #pragma unroll
            for (int m = 0; m < 4; ++m)
                a[m] = *reinterpret_cast<const bf16x8*>(&h_lds[(m*16 + c) * LDH + kc*32 + g*8]);
            #pragma unroll
            for (int nl = 0; nl < 3; ++nl) {
                int nt = wv * 3 + nl;
                bf16x8 b = *reinterpret_cast<const bf16x8*>(&wkvt[(nt*16 + c) * 96 + kc*32 + g*8]);
                #pragma unroll
                for (int m = 0; m < 4; ++m)
                    acc[m][nl] = MFMA(a[m], b, acc[m][nl]);
            }
        }
        #pragma unroll
        for (int nl = 0; nl < 3; ++nl) {
            int n = (wv * 3 + nl) * 16 + c;
            float bias = bkv[n];
            if (wv < 2) {  // k rows (n in [0,96))
                #pragma unroll
                for (int m = 0; m < 4; ++m)
                    #pragma unroll
                    for (int r = 0; r < 4; ++r)
                        k_lds[(m*16 + g*4 + r) * LDH + n] = (__bf16)(acc[m][nl][r] + bias);
            } else {       // v transposed (n-96 in [0,96))
                int nv = n - 96;
                #pragma unroll
                for (int m = 0; m < 4; ++m) {
                    bf16x4 pk;
                    pk.x = (__bf16)(acc[m][nl][0] + bias);
                    pk.y = (__bf16)(acc[m][nl][1] + bias);
                    pk.z = (__bf16)(acc[m][nl][2] + bias);
                    pk.w = (__bf16)(acc[m][nl][3] + bias);
                    *reinterpret_cast<bf16x4*>(&vt_lds[nv * 72 + m*16 + g*4]) = pk;
                }
            }
        }
    }
    __syncthreads();

    // ---- per head: QK^T + in-register softmax + PV (per-wave P scratch, no barrier) ----
    __bf16* p_w = &p_lds[wv * (16 * 72)];
    #pragma unroll
    for (int h = 0; h < 3; ++h) {
        f32x4 sacc[4];
        #pragma unroll
        for (int nt = 0; nt < 4; ++nt) sacc[nt] = (f32x4){0.f, 0.f, 0.f, 0.f};
        bf16x8 a = *reinterpret_cast<const bf16x8*>(&q_lds[(wv*16 + c) * LDH + h*32 + g*8]);
        #pragma unroll
        for (int nt = 0; nt < 4; ++nt) {
            bf16x8 b = *reinterpret_cast<const bf16x8*>(&k_lds[(nt*16 + c) * LDH + h*32 + g*8]);
            sacc[nt] = MFMA(a, b, sacc[nt]);
        }
        float mx[4];
        #pragma unroll
        for (int r = 0; r < 4; ++r) {
            float m0 = fmaxf(fmaxf(sacc[0][r], sacc[1][r]), fmaxf(sacc[2][r], sacc[3][r]));
            m0 = fmaxf(m0, __shfl_xor(m0, 1));
            m0 = fmaxf(m0, __shfl_xor(m0, 2));
            m0 = fmaxf(m0, __shfl_xor(m0, 4));
            m0 = fmaxf(m0, __shfl_xor(m0, 8));
            mx[r] = m0;
        }
        float p[4][4];
        #pragma unroll
        for (int nt = 0; nt < 4; ++nt)
            #pragma unroll
            for (int r = 0; r < 4; ++r)
                p[nt][r] = __expf(sacc[nt][r] - mx[r]);
        float rsinv[4];
        #pragma unroll
        for (int r = 0; r < 4; ++r) {
            float s0 = p[0][r] + p[1][r] + p[2][r] + p[3][r];
            s0 += __shfl_xor(s0, 1); s0 += __shfl_xor(s0, 2);
            s0 += __shfl_xor(s0, 4); s0 += __shfl_xor(s0, 8);
            rsinv[r] = __builtin_amdgcn_rcpf(s0);
        }
        #pragma unroll
        for (int nt = 0; nt < 4; ++nt)
            #pragma unroll
            for (int r = 0; r < 4; ++r)
                p_w[(g*4 + r) * 72 + nt*16 + c] = (__bf16)p[nt][r];

        f32x4 oacc[2];
        oacc[0] = (f32x4){0.f, 0.f, 0.f, 0.f};
        oacc[1] = (f32x4){0.f, 0.f, 0.f, 0.f};
        #pragma unroll
        for (int kc = 0; kc < 2; ++kc) {
            bf16x8 pa = *reinterpret_cast<const bf16x8*>(&p_w[c * 72 + kc*32 + g*8]);
            #pragma unroll
            for (int n2 = 0; n2 < 2; ++n2) {
                bf16x8 b = *reinterpret_cast<const bf16x8*>(&vt_lds[(h*32 + n2*16 + c) * 72 + kc*32 + g*8]);
                oacc[n2] = MFMA(pa, b, oacc[n2]);
            }
        }
        #pragma unroll
        for (int n2 = 0; n2 < 2; ++n2)
            #pragma unroll
            for (int r = 0; r < 4; ++r)
                h_lds[(wv*16 + g*4 + r) * LDH + h*32 + n2*16 + c] = (__bf16)(oacc[n2][r] * rsinv[r]);
    }
    __syncthreads();

    // ---- proj: out = attnout @ wpt + bp -> q_lds ----
    {
        f32x4 acc[2][3];
        #pragma unroll
        for (int mi = 0; mi < 2; ++mi)
            #pragma unroll
            for (int nl = 0; nl < 3; ++nl) acc[mi][nl] = (f32x4){0.f, 0.f, 0.f, 0.f};
        #pragma unroll
        for (int kc = 0; kc < 3; ++kc) {
            bf16x8 a[2];
            #pragma unroll
            for (int mi = 0; mi < 2; ++mi)
                a[mi] = *reinterpret_cast<const bf16x8*>(&h_lds[((mp*2+mi)*16 + c) * LDH + kc*32 + g*8]);
            #pragma unroll
            for (int nl = 0; nl < 3; ++nl) {
                int nt = ng * 3 + nl;
                bf16x8 b = *reinterpret_cast<const bf16x8*>(&wpt[(nt*16 + c) * 96 + kc*32 + g*8]);
                #pragma unroll
                for (int mi = 0; mi < 2; ++mi)
                    acc[mi][nl] = MFMA(a[mi], b, acc[mi][nl]);
            }
        }
        __syncthreads();
        #pragma unroll
        for (int nl = 0; nl < 3; ++nl) {
            int n = (ng * 3 + nl) * 16 + c;
            float bias = bp[n];
            #pragma unroll
            for (int mi = 0; mi < 2; ++mi)
                #pragma unroll
                for (int r = 0; r < 4; ++r)
                    q_lds[((mp*2+mi)*16 + g*4 + r) * LDH + n] = (__bf16)(acc[mi][nl][r] + bias);
        }
    }
    __syncthreads();

    // ---- residual: xmid = x + attn_out ----
    #pragma unroll
    for (int j = 0; j < 6; ++j) {
        float4 v;
        v.x = xr[j*4+0] + (float)q_lds[tok * LDH + cseg + j*4+0];
        v.y = xr[j*4+1] + (float)q_lds[tok * LDH + cseg + j*4+1];
        v.z = xr[j*4+2] + (float)q_lds[tok * LDH + cseg + j*4+2];
        v.w = xr[j*4+3] + (float)q_lds[tok * LDH + cseg + j*4+3];
        *reinterpret_cast<float4*>(xmid + gbase + j * 4) = v;
    }
}

extern "C" void kernel_launch(void* const* d_in, const int* in_sizes, int n_in,
                              void* d_out, int out_size, void* d_ws, size_t ws_size,
                              hipStream_t stream) {
    (void)in_sizes; (void)n_in; (void)out_size; (void)ws_size;
    const float* x   = (const float*)d_in[0];
    const float* g1  = (const float*)d_in[1];
    const float* b1  = (const float*)d_in[2];
    const float* wq  = (const float*)d_in[3];
    const float* bq  = (const float*)d_in[4];
    const float* wkv = (const float*)d_in[5];
    const float* bkv = (const float*)d_in[6];
    const float* wp  = (const float*)d_in[7];
    const float* bp  = (const float*)d_in[8];
    const float* g2  = (const float*)d_in[9];
    const float* b2  = (const float*)d_in[10];
    const float* w1  = (const float*)d_in[11];
    const float* bm1 = (const float*)d_in[12];
    const float* w2  = (const float*)d_in[13];
    const float* bm2 = (const float*)d_in[14];
    float* out = (float*)d_out;
    __bf16* ws = (__bf16*)d_ws;

    prep_weights<<<432, 256, 0, stream>>>(wq, wkv, wp, w1, w2, ws);
    attn_kernel<<<9216, 256, 0, stream>>>(x, g1, b1, bq, bkv, bp, ws, out);
    mlp_kernel<<<9216, 384, 0, stream>>>(out, g2, b2, bm1, bm2, ws);
}